// Round 9
// baseline (892.323 us; speedup 1.0000x reference)
//
#include <hip/hip_runtime.h>

// SAGE 3-layer GNN, N=100000 nodes, E=1600000 edges, d: 64 -> 64 -> 64 -> 32.
// CSR (dst -> srcs) built once per call.
// Features stored CHUNK-MAJOR: hT[chunk c][node n][8 floats], c = f>>3.
// Aggregation runs 8 feature-passes (blockIdx.y); each pass touches a 3.2 MB
// chunk region that fits the 4 MB per-XCD L2 -> gather reads become L2 hits.
// gemm reads/writes chunk-major; final layer writes row-major to d_out.

#define NN 100000
#define NE 1600000
#define GEMM_BLOCKS 1024
#define CS ((size_t)NN * 8)   // floats per chunk plane

// ---------------- CSR construction ----------------

__global__ __launch_bounds__(256) void deg_count_kernel(
    const int* __restrict__ dst, int* __restrict__ deg, int n_edges) {
  int e = blockIdx.x * 256 + threadIdx.x;
  if (e < n_edges) atomicAdd(&deg[dst[e]], 1);
}

__global__ __launch_bounds__(256) void scan_partial_kernel(
    const int* __restrict__ deg, int* __restrict__ partials, int n_nodes) {
  __shared__ int sb[256];
  int t = threadIdx.x;
  int i = blockIdx.x * 256 + t;
  sb[t] = (i < n_nodes) ? deg[i] : 0;
  __syncthreads();
  for (int off = 128; off > 0; off >>= 1) {
    if (t < off) sb[t] += sb[t + off];
    __syncthreads();
  }
  if (t == 0) partials[blockIdx.x] = sb[0];
}

__global__ __launch_bounds__(512) void scan_top_kernel(
    int* __restrict__ partials, int nb, int* __restrict__ rowp, int n_nodes) {
  __shared__ int tmp[512];
  int t = threadIdx.x;
  int v = (t < nb) ? partials[t] : 0;
  tmp[t] = v;
  __syncthreads();
  for (int off = 1; off < 512; off <<= 1) {
    int add = (t >= off) ? tmp[t - off] : 0;
    __syncthreads();
    tmp[t] += add;
    __syncthreads();
  }
  if (t < nb) partials[t] = tmp[t] - v;      // exclusive block offsets
  if (t == 511) rowp[n_nodes] = tmp[511];    // total edge count
}

__global__ __launch_bounds__(256) void scan_final_kernel(
    const int* __restrict__ deg, const int* __restrict__ partials,
    int* __restrict__ rowp, int* __restrict__ cursor,
    float* __restrict__ degf, int n_nodes) {
  __shared__ int tmp[256];
  int t = threadIdx.x;
  int i = blockIdx.x * 256 + t;
  int v = (i < n_nodes) ? deg[i] : 0;
  tmp[t] = v;
  __syncthreads();
  for (int off = 1; off < 256; off <<= 1) {
    int add = (t >= off) ? tmp[t - off] : 0;
    __syncthreads();
    tmp[t] += add;
    __syncthreads();
  }
  if (i < n_nodes) {
    int exc = tmp[t] - v + partials[blockIdx.x];
    rowp[i] = exc;
    cursor[i] = exc;
    degf[i] = fmaxf((float)v, 1.0f);
  }
}

__global__ __launch_bounds__(256) void fill_kernel(
    const int* __restrict__ src, const int* __restrict__ dst,
    int* __restrict__ cursor, int* __restrict__ col, int n_edges) {
  int e = blockIdx.x * 256 + threadIdx.x;
  if (e < n_edges) {
    int pos = atomicAdd(&cursor[dst[e]], 1);
    col[pos] = src[e];
  }
}

// ---------------- layout transpose: row-major -> chunk-major ----------------
// x[n][64] -> xT[f>>3][n][f&7]

__global__ __launch_bounds__(256) void to_chunk_major_kernel(
    const float* __restrict__ x, float* __restrict__ xT) {
  int t = blockIdx.x * 256 + threadIdx.x;   // t < NN*64, grid exact
  int n = t >> 6;
  int f = t & 63;
  xT[(size_t)(f >> 3) * CS + (size_t)n * 8 + (f & 7)] = x[t];
}

// ---------------- aggregation: mean over in-neighbors (chunk-major) --------
// blockIdx.y = feature pass p (chunk). 2 lanes per node (h = lane&1, float4).
// Per pass, gathers touch only chunk p's 3.2 MB region -> L2-resident.

__global__ __launch_bounds__(256) void agg_chunked_kernel(
    const float* __restrict__ hT,        // [8][N][8] chunk-major
    const int* __restrict__ rowp,        // [N+1]
    const int* __restrict__ col,         // [E]
    const float* __restrict__ degf,      // [N] max(deg,1)
    float* __restrict__ meanT) {         // [8][N][8] chunk-major
  const int p = blockIdx.y;
  const int n = blockIdx.x * 128 + (threadIdx.x >> 1);
  const int h = threadIdx.x & 1;
  if (n >= NN) return;

  const float* base = hT + (size_t)p * CS + (size_t)h * 4;
  const int e0 = rowp[n];
  const int e1 = rowp[n + 1];

  float ax = 0.f, ay = 0.f, az = 0.f, aw = 0.f;
  int e = e0;
  for (; e + 4 <= e1; e += 4) {     // 4 independent gathers in flight
    int i0 = col[e], i1 = col[e + 1], i2 = col[e + 2], i3 = col[e + 3];
    float4 v0 = *(const float4*)(base + (size_t)i0 * 8);
    float4 v1 = *(const float4*)(base + (size_t)i1 * 8);
    float4 v2 = *(const float4*)(base + (size_t)i2 * 8);
    float4 v3 = *(const float4*)(base + (size_t)i3 * 8);
    ax += (v0.x + v1.x) + (v2.x + v3.x);
    ay += (v0.y + v1.y) + (v2.y + v3.y);
    az += (v0.z + v1.z) + (v2.z + v3.z);
    aw += (v0.w + v1.w) + (v2.w + v3.w);
  }
  for (; e < e1; ++e) {
    float4 v = *(const float4*)(base + (size_t)col[e] * 8);
    ax += v.x; ay += v.y; az += v.z; aw += v.w;
  }

  const float d = degf[n];
  float4 mv = {ax / d, ay / d, az / d, aw / d};
  *(float4*)(meanT + (size_t)p * CS + (size_t)n * 8 + (size_t)h * 4) = mv;
}

// ---------------- dual GEMM: [self|mean] @ [Wself;Wneigh] + b ----------------
// persistent blocks; Wt[c][k] transposed+padded staged once per block.
// h_self/mean read chunk-major. DOUT=64 writes chunk-major; DOUT=32 writes
// row-major (final output).

template <int DOUT, bool RELU>
__global__ __launch_bounds__(256) void gemm_kernel(
    const float* __restrict__ hT_self,    // [8][N][8] chunk-major
    const float* __restrict__ meanT,      // [8][N][8] chunk-major
    const float* __restrict__ Wself,      // [64, DOUT]
    const float* __restrict__ Wneigh,     // [64, DOUT]
    const float* __restrict__ bias,       // [DOUT]
    float* __restrict__ h_out) {          // chunk-major [8][N][8] or row-major [N,32]
  __shared__ float Wt[DOUT][132];         // Wt[c][k] = Wcat[k][c]
  __shared__ float rowbuf[4][128];        // per-wave [self(64)|mean(64)]

  const int tid  = threadIdx.x;
  const int wave = tid >> 6;
  const int lane = tid & 63;

  for (int idx = tid; idx < DOUT * 128; idx += 256) {
    int c = idx & (DOUT - 1);
    int k = idx / DOUT;
    Wt[c][k] = (k < 64) ? Wself[k * DOUT + c] : Wneigh[(k - 64) * DOUT + c];
  }
  __syncthreads();

  const float bval = (lane < DOUT) ? bias[lane] : 0.0f;
  const size_t coff = (size_t)(lane >> 3) * CS + (size_t)(lane & 7);

  for (int gblk = blockIdx.x; gblk < NN / 4; gblk += GEMM_BLOCKS) {
    const int n = gblk * 4 + wave;
    rowbuf[wave][lane]      = hT_self[coff + (size_t)n * 8];
    rowbuf[wave][64 + lane] = meanT[coff + (size_t)n * 8];
    // per-wave LDS only: compiler-inserted lgkmcnt orders write->read

    if (lane < DOUT) {
      float o0 = 0.f, o1 = 0.f, o2 = 0.f, o3 = 0.f;
#pragma unroll
      for (int j = 0; j < 32; ++j) {
        const float4 w = *(const float4*)&Wt[lane][j * 4];
        const float4 r = *(const float4*)&rowbuf[wave][j * 4];
        o0 = fmaf(r.x, w.x, o0);
        o1 = fmaf(r.y, w.y, o1);
        o2 = fmaf(r.z, w.z, o2);
        o3 = fmaf(r.w, w.w, o3);
      }
      float o = ((o0 + o1) + (o2 + o3)) + bval;
      if (RELU) o = fmaxf(o, 0.0f);
      if (DOUT == 64) {
        h_out[(size_t)(lane >> 3) * CS + (size_t)n * 8 + (lane & 7)] = o;
      } else {
        h_out[(size_t)n * DOUT + lane] = o;   // final layer: row-major
      }
    }
  }
}

// ---------------- launch ----------------

extern "C" void kernel_launch(void* const* d_in, const int* in_sizes, int n_in,
                              void* d_out, int out_size, void* d_ws, size_t ws_size,
                              hipStream_t stream) {
  const float* x   = (const float*)d_in[0];
  const int*   src = (const int*)d_in[1];
  const int*   dst = (const int*)d_in[2];
  const float* Ws1 = (const float*)d_in[3];
  const float* Wn1 = (const float*)d_in[4];
  const float* b1  = (const float*)d_in[5];
  const float* Ws2 = (const float*)d_in[6];
  const float* Wn2 = (const float*)d_in[7];
  const float* b2  = (const float*)d_in[8];
  const float* Ws3 = (const float*)d_in[9];
  const float* Wn3 = (const float*)d_in[10];
  const float* b3  = (const float*)d_in[11];
  float* out = (float*)d_out;

  char* ws = (char*)d_ws;
  size_t off = 0;
  auto take = [&](size_t bytes) -> void* {
    void* p = ws + off;
    off += (bytes + 255) & ~(size_t)255;
    return p;
  };
  int*   deg      = (int*)take((size_t)NN * 4);
  float* degf     = (float*)take((size_t)NN * 4);
  int*   rowp     = (int*)take((size_t)(NN + 1) * 4);
  int*   cursor   = (int*)take((size_t)NN * 4);
  int*   partials = (int*)take(1024 * 4);
  int*   col      = (int*)take((size_t)NE * 4);
  float* bufA     = (float*)take((size_t)NN * 64 * 4);  // xT, later h2T
  float* bufB     = (float*)take((size_t)NN * 64 * 4);  // h1T
  float* meanT    = (float*)take((size_t)NN * 64 * 4);
  (void)ws_size; (void)in_sizes; (void)n_in; (void)out_size;

  hipMemsetAsync(deg, 0, (size_t)NN * 4, stream);

  const int EB = (NE + 255) / 256;        // 6250
  const int NB = (NN + 255) / 256;        // 391
  const dim3 AG((NN + 127) / 128, 8, 1);  // 782 x 8 passes

  deg_count_kernel<<<EB, 256, 0, stream>>>(dst, deg, NE);
  scan_partial_kernel<<<NB, 256, 0, stream>>>(deg, partials, NN);
  scan_top_kernel<<<1, 512, 0, stream>>>(partials, NB, rowp, NN);
  scan_final_kernel<<<NB, 256, 0, stream>>>(deg, partials, rowp, cursor, degf, NN);
  fill_kernel<<<EB, 256, 0, stream>>>(src, dst, cursor, col, NE);

  to_chunk_major_kernel<<<NN * 64 / 256, 256, 0, stream>>>(x, bufA);

  // layer 1: x(=bufA) -> h1(=bufB)
  agg_chunked_kernel<<<AG, 256, 0, stream>>>(bufA, rowp, col, degf, meanT);
  gemm_kernel<64, false><<<GEMM_BLOCKS, 256, 0, stream>>>(bufA, meanT, Ws1, Wn1, b1, bufB);

  // layer 2: h1(=bufB) -> h2(=bufA, xT is dead)
  agg_chunked_kernel<<<AG, 256, 0, stream>>>(bufB, rowp, col, degf, meanT);
  gemm_kernel<64, false><<<GEMM_BLOCKS, 256, 0, stream>>>(bufB, meanT, Ws2, Wn2, b2, bufA);

  // layer 3: h2(=bufA) -> out (row-major)
  agg_chunked_kernel<<<AG, 256, 0, stream>>>(bufA, rowp, col, degf, meanT);
  gemm_kernel<32, true ><<<GEMM_BLOCKS, 256, 0, stream>>>(bufA, meanT, Ws3, Wn3, b3, out);
}